// Round 3
// baseline (508.887 us; speedup 1.0000x reference)
//
#include <hip/hip_runtime.h>
#include <math.h>

// ============================ PROBE ROUND ============================
// Kernel body is BYTE-IDENTICAL to the best variant (R1, 370.45 us).
// kernel_launch launches it 3x back-to-back as a TIMING PROBE:
//   dur_us - 370.45 = 2 x kF_warm  (kF is idempotent; output unchanged)
// This measures how much of the per-iteration budget kF actually uses,
// vs fixed harness fills (~282 us) + ~100 tiny dispatches.
// NEXT ROUND: strip the extra launches.
// =====================================================================

// Problem constants
#define Bb 8
#define Kk 32
#define Hh 480
#define Ww 480
#define Nn 576
#define Dd 1024
#define CLSD 64
#define OUTD 256
#define INDIM 1093
#define BK 256           // B*K

typedef int v4i __attribute__((ext_vector_type(4)));

__global__ __launch_bounds__(1024) void kF(const int* __restrict__ masks,
                                           const float* __restrict__ fm,
                                           const int* __restrict__ cids,
                                           const float* __restrict__ emb,
                                           const float* __restrict__ W1,
                                           const float* __restrict__ b1,
                                           const float* __restrict__ lg,
                                           const float* __restrict__ lb,
                                           const float* __restrict__ W2,
                                           const float* __restrict__ b2,
                                           float* __restrict__ out) {
  const int b    = blockIdx.x & 7;
  const int k    = blockIdx.x >> 3;
  const int bk   = b * Kk + k;
  const int t    = threadIdx.x;
  const int lane = t & 63;
  const int w    = t >> 6;          // wave id 0..15

  __shared__ int    actw[4][576];   // per-consumer-wave act lists (9.2 KB)
  __shared__ float4 x4s[256];       // per-consumer-wave x staging (4 KB)
  __shared__ float  partial[16 * 256]; // GEMV partials (16 KB)
  __shared__ float  hrow[256];
  __shared__ float  red_s[4], red_q[4];
  __shared__ float  gmeta[8];
  __shared__ int    gstat[12][7];   // per-scan-wave area,sumx,sumy,minx,maxx,miny,maxy

  const int* mbase = masks + (size_t)bk * (Hh * Ww);

  if (w < 12) {
    // ============ SCAN (768 threads, 75 clean iterations, nt loads) ========
    int area = 0, sumx = 0, sumy = 0;
    int minx = Ww, maxx = -1, miny = Hh, maxy = -1;
    const v4i* mp = (const v4i*)mbase;
#pragma unroll 5
    for (int i = 0; i < 75; i++) {
      int q = t + i * 768;
      v4i v = __builtin_nontemporal_load(mp + q);
      int h   = q / 120;            // 120 int4 per row (magic-mul)
      int rem = q - h * 120;
      int w0  = rem * 4;
      int m0 = v.x > 0, m1 = v.y > 0, m2 = v.z > 0, m3 = v.w > 0;
      int c = m0 + m1 + m2 + m3;
      area += c;
      sumy += h * c;
      sumx += w0 * c + m1 + 2 * m2 + 3 * m3;
      if (c) {
        miny = min(miny, h);
        maxy = max(maxy, h);
        int lo = m0 ? w0 : (m1 ? w0 + 1 : (m2 ? w0 + 2 : w0 + 3));
        int hi = m3 ? w0 + 3 : (m2 ? w0 + 2 : (m1 ? w0 + 1 : w0));
        minx = min(minx, lo);
        maxx = max(maxx, hi);
      }
    }
    for (int off = 32; off; off >>= 1) {
      area += __shfl_down(area, off);
      sumx += __shfl_down(sumx, off);
      sumy += __shfl_down(sumy, off);
      minx = min(minx, __shfl_down(minx, off));
      maxx = max(maxx, __shfl_down(maxx, off));
      miny = min(miny, __shfl_down(miny, off));
      maxy = max(maxy, __shfl_down(maxy, off));
    }
    if (lane == 0) {
      gstat[w][0] = area; gstat[w][1] = sumx; gstat[w][2] = sumy;
      gstat[w][3] = minx; gstat[w][4] = maxx;
      gstat[w][5] = miny; gstat[w][6] = maxy;
    }
  } else {
    // ============ CONSUMER (4 waves): sample + pool + GEMV1 K<1024 =========
    const int cw   = w - 12;        // 0..3
    const int base = cw * 64 + lane;  // float4 col index owned by this lane

    // --- per-wave act list: 9 rounds of ballot compaction (no barrier) ---
    int mv[9];
#pragma unroll
    for (int r = 0; r < 9; r++) {
      int p = r * 64 + lane;        // p < 576 always
      int a = p / 24, c = p - a * 24;
      mv[r] = mbase[(a * 20) * Ww + c * 20];
    }
    int na = 0;
    int* actp = actw[cw];
#pragma unroll
    for (int r = 0; r < 9; r++) {
      unsigned long long bal = __ballot(mv[r] > 0);
      int idx = __popcll(bal & ((1ull << lane) - 1));
      if (mv[r] > 0) actp[na + idx] = r * 64 + lane;
      na += __popcll(bal);
    }

    // --- pooling over own list (ascending row order, L2-served fm) ---
    const float4* fmp = (const float4*)fm + (size_t)b * Nn * (Dd / 4);
    float ax = 0.f, ay = 0.f, az = 0.f, aw = 0.f;
    int j = 0;
    for (; j + 4 <= na; j += 4) {
      int n0 = actp[j], n1 = actp[j + 1], n2 = actp[j + 2], n3 = actp[j + 3];
      float4 f0 = fmp[n0 * (Dd / 4) + base];
      float4 f1 = fmp[n1 * (Dd / 4) + base];
      float4 f2 = fmp[n2 * (Dd / 4) + base];
      float4 f3 = fmp[n3 * (Dd / 4) + base];
      ax += f0.x + f1.x + f2.x + f3.x;
      ay += f0.y + f1.y + f2.y + f3.y;
      az += f0.z + f1.z + f2.z + f3.z;
      aw += f0.w + f1.w + f2.w + f3.w;
    }
    for (; j < na; j++) {
      float4 f = fmp[actp[j] * (Dd / 4) + base];
      ax += f.x; ay += f.y; az += f.z; aw += f.w;
    }
    float inv = 1.0f / fmaxf((float)na, 1e-6f);
    float4 xp;
    xp.x = ax * inv; xp.y = ay * inv; xp.z = az * inv; xp.w = aw * inv;
    x4s[base] = xp;                 // same-wave LDS stage (no barrier needed)

    // --- GEMV1 over this wave's own K-slice [256cw, 256cw+256) ---
    float4 acc = {0.f, 0.f, 0.f, 0.f};
    const float* W1b = W1 + (size_t)(cw * 256) * OUTD + 4 * lane;
#pragma unroll 2
    for (int g = 0; g < 64; g++) {
      float4 xv = x4s[cw * 64 + g]; // wave-uniform LDS broadcast
      const float* xs = (const float*)&xv;
#pragma unroll
      for (int u = 0; u < 4; u++) {
        float4 w4 = *(const float4*)(W1b + (size_t)(4 * g + u) * OUTD);
        acc.x = fmaf(xs[u], w4.x, acc.x);
        acc.y = fmaf(xs[u], w4.y, acc.y);
        acc.z = fmaf(xs[u], w4.z, acc.z);
        acc.w = fmaf(xs[u], w4.w, acc.w);
      }
    }
    *(float4*)(partial + cw * 256 + 4 * lane) = acc;
  }
  __syncthreads();

  // ---------------- Epilogue ----------------
  if (t == 0) {
    int area = 0, sumx = 0, sumy = 0;
    int minx = Ww, maxx = -1, miny = Hh, maxy = -1;
#pragma unroll
    for (int i = 0; i < 12; i++) {
      area += gstat[i][0]; sumx += gstat[i][1]; sumy += gstat[i][2];
      minx = min(minx, gstat[i][3]); maxx = max(maxx, gstat[i][4]);
      miny = min(miny, gstat[i][5]); maxy = max(maxy, gstat[i][6]);
    }
    float areaf = (float)area;
    float safe  = fmaxf(areaf, 1.0f);
    float cx = ((float)sumx / safe) * (1.0f / Ww);
    float cy = ((float)sumy / safe) * (1.0f / Hh);
    float an = areaf * (1.0f / (Hh * Ww));
    float bw = (float)(maxx - minx + 1) * (1.0f / Ww);
    float bh = (float)(maxy - miny + 1) * (1.0f / Hh);
    if (area < 1) { cx = 0.f; cy = 0.f; an = 0.f; bw = 0.f; bh = 0.f; }
    gmeta[0] = cx; gmeta[1] = cy; gmeta[2] = an; gmeta[3] = bw; gmeta[4] = bh;
  }
  __syncthreads();

  // combine + cls/geom GEMV1 tail + GeLU  (threads 0..255)
  float hv = 0.f;
  if (t < 256) {
    hv = b1[t] + partial[t] + partial[256 + t] + partial[512 + t] + partial[768 + t];
    const float* et = emb + (size_t)cids[bk] * CLSD;
#pragma unroll 8
    for (int i = 0; i < CLSD; i++)
      hv = fmaf(et[i], W1[(size_t)(Dd + i) * OUTD + t], hv);
#pragma unroll
    for (int jj = 0; jj < 5; jj++)
      hv = fmaf(gmeta[jj], W1[(size_t)(Dd + CLSD + jj) * OUTD + t], hv);
    hv = 0.5f * hv * (1.0f + erff(hv * 0.7071067811865475f));
  }
  {
    float s = hv, q = hv * hv;
    for (int off = 32; off; off >>= 1) {
      s += __shfl_down(s, off);
      q += __shfl_down(q, off);
    }
    if (lane == 0 && w < 4) { red_s[w] = s; red_q[w] = q; }
  }
  __syncthreads();
  if (t < 256) {
    float s = red_s[0] + red_s[1] + red_s[2] + red_s[3];
    float q = red_q[0] + red_q[1] + red_q[2] + red_q[3];
    float mu  = s * (1.0f / OUTD);
    float var = q * (1.0f / OUTD) - mu * mu;
    float ist = 1.0f / sqrtf(var + 1e-5f);
    hrow[t] = (hv - mu) * ist * lg[t] + lb[t];
  }
  __syncthreads();

  // GEMV2: 16-way wave K-split, float4 W2 loads
  {
    float4 acc = {0.f, 0.f, 0.f, 0.f};
#pragma unroll
    for (int i = 0; i < 4; i++) {
      float4 h4 = ((const float4*)hrow)[w * 4 + i];
      const float* hs = (const float*)&h4;
#pragma unroll
      for (int u = 0; u < 4; u++) {
        int kk = w * 16 + i * 4 + u;
        float4 w4 = *(const float4*)(W2 + (size_t)kk * OUTD + 4 * lane);
        acc.x = fmaf(hs[u], w4.x, acc.x);
        acc.y = fmaf(hs[u], w4.y, acc.y);
        acc.z = fmaf(hs[u], w4.z, acc.z);
        acc.w = fmaf(hs[u], w4.w, acc.w);
      }
    }
    *(float4*)(partial + w * 256 + 4 * lane) = acc;
  }
  __syncthreads();

  if (t < 256) {
    float c = b2[t];
#pragma unroll
    for (int ww = 0; ww < 16; ww++) c += partial[ww * 256 + t];
    __builtin_nontemporal_store(c, out + (size_t)bk * OUTD + t);
  }
}

extern "C" void kernel_launch(void* const* d_in, const int* in_sizes, int n_in,
                              void* d_out, int out_size, void* d_ws, size_t ws_size,
                              hipStream_t stream) {
  const float* fm    = (const float*)d_in[0];
  const int*   masks = (const int*)d_in[1];
  const int*   cids  = (const int*)d_in[2];
  const float* emb   = (const float*)d_in[3];
  const float* W1    = (const float*)d_in[4];
  const float* b1    = (const float*)d_in[5];
  const float* lg    = (const float*)d_in[6];
  const float* lb    = (const float*)d_in[7];
  const float* W2    = (const float*)d_in[8];
  const float* b2    = (const float*)d_in[9];
  float* out = (float*)d_out;

  // PROBE: 3 identical launches. dur_us - 370.45 = 2 x kF_warm.
  // kF is idempotent -> output identical; strip extra launches next round.
  hipLaunchKernelGGL(kF, dim3(BK), dim3(1024), 0, stream, masks, fm, cids, emb,
                     W1, b1, lg, lb, W2, b2, out);
  hipLaunchKernelGGL(kF, dim3(BK), dim3(1024), 0, stream, masks, fm, cids, emb,
                     W1, b1, lg, lb, W2, b2, out);
  hipLaunchKernelGGL(kF, dim3(BK), dim3(1024), 0, stream, masks, fm, cids, emb,
                     W1, b1, lg, lb, W2, b2, out);
}

// Round 5
// 389.924 us; speedup vs baseline: 1.3051x; 1.3051x over previous
//
#include <hip/hip_runtime.h>
#include <math.h>

// Problem constants
#define Bb 8
#define Kk 32
#define Hh 480
#define Ww 480
#define Nn 576
#define Dd 1024
#define CLSD 64
#define OUTD 256
#define BK 256           // B*K

typedef int v4i __attribute__((ext_vector_type(4)));

// Address-space-qualified pointer types for global_load_lds
typedef __attribute__((address_space(1))) const int gas_int;
typedef __attribute__((address_space(3))) int las_int;

// -------- dynamic-LDS carve (bytes) --------
// dma: 12 scan waves x 8 slots x 1KB (depth-8 DMA pipeline)
#define OFF_DMA     0        // 98304 B
#define OFF_ACTW    98304    // 4*576*4  = 9216
#define OFF_X4S     107520   // 256*16   = 4096
#define OFF_PART    111616   // 16*256*4 = 16384
#define OFF_HROW    128000   // 256*4    = 1024
#define OFF_REDS    129024   // 16
#define OFF_REDQ    129040   // 16
#define OFF_GMETA   129056   // 32
#define OFF_GSTAT   129088   // 12*7*4   = 336
#define SMEM_BYTES  129536

// Overlap-structured fused kernel (R1 structure), scan rewritten to use the
// async global->LDS DMA path:
//   THEORY: the scan was capped at ~13 GB/s/CU (225MiB in ~64us = 3.5TB/s) by
//   the per-CU outstanding-miss capacity of the VGPR-return load path
//   (~230 lines x 64B / ~1.1us loaded latency). global_load_lds is
//   vmcnt-tracked per instruction into LDS; a depth-8/wave pipeline holds
//   96KB/CU in flight (3.5x what full-rate HBM needs at 1.1us latency).
//   Waves 0-11: DMA scan (issue 8 ahead -> vmcnt(7) -> ds_read own 16B ->
//               stats -> reissue). Waves 12-15: act-list + pooling + GEMV1.
__global__ __launch_bounds__(1024) void kF(const int* __restrict__ masks,
                                           const float* __restrict__ fm,
                                           const int* __restrict__ cids,
                                           const float* __restrict__ emb,
                                           const float* __restrict__ W1,
                                           const float* __restrict__ b1,
                                           const float* __restrict__ lg,
                                           const float* __restrict__ lb,
                                           const float* __restrict__ W2,
                                           const float* __restrict__ b2,
                                           float* __restrict__ out) {
  const int b    = blockIdx.x & 7;
  const int k    = blockIdx.x >> 3;
  const int bk   = b * Kk + k;
  const int t    = threadIdx.x;
  const int lane = t & 63;
  const int w    = t >> 6;          // wave id 0..15

  extern __shared__ char smem[];
  int*    dma     = (int*)(smem + OFF_DMA);
  int*    actw    = (int*)(smem + OFF_ACTW);
  float4* x4s     = (float4*)(smem + OFF_X4S);
  float*  partial = (float*)(smem + OFF_PART);
  float*  hrow    = (float*)(smem + OFF_HROW);
  float*  red_s   = (float*)(smem + OFF_REDS);
  float*  red_q   = (float*)(smem + OFF_REDQ);
  float*  gmeta   = (float*)(smem + OFF_GMETA);
  int*    gstat   = (int*)(smem + OFF_GSTAT);

  const int* mbase = masks + (size_t)bk * (Hh * Ww);

  if (w < 12) {
    // ============ SCAN via depth-8 global_load_lds pipeline ============
    // wave w owns int4 range [w*4800, (w+1)*4800) = 75 chunks of 64 int4.
    const int g0   = w * 4800;
    int* dmaW      = dma + w * 2048;                    // 8 slots * 256 ints
    const char* gsrc0 = (const char*)mbase + (size_t)(g0 + lane) * 16;

#define ISSUE(cc)                                                        \
    __builtin_amdgcn_global_load_lds(                                    \
        (gas_int*)(gsrc0 + (size_t)(cc) * 1024),                         \
        (las_int*)(dmaW + (((cc) & 7) << 8)), 16, 0, 0)

#define STAT_BODY(cc)                                                    \
    {                                                                    \
      v4i v = *(const v4i*)(dmaW + (((cc) & 7) << 8) + lane * 4);        \
      int g    = g0 + (cc) * 64 + lane;                                  \
      int h    = g / 120;           /* 120 int4 per row */               \
      int rem  = g - h * 120;                                            \
      int w0   = rem * 4;                                                \
      int m0 = v.x > 0, m1 = v.y > 0, m2 = v.z > 0, m3 = v.w > 0;        \
      int cnt = m0 + m1 + m2 + m3;                                       \
      area += cnt;                                                       \
      sumy += h * cnt;                                                   \
      sumx += w0 * cnt + m1 + 2 * m2 + 3 * m3;                           \
      if (cnt) {                                                         \
        miny = min(miny, h);                                             \
        maxy = max(maxy, h);                                             \
        int lo = m0 ? w0 : (m1 ? w0 + 1 : (m2 ? w0 + 2 : w0 + 3));       \
        int hi = m3 ? w0 + 3 : (m2 ? w0 + 2 : (m1 ? w0 + 1 : w0));       \
        minx = min(minx, lo);                                            \
        maxx = max(maxx, hi);                                            \
      }                                                                  \
    }

    // prologue: fill the 8-deep pipe
#pragma unroll
    for (int s = 0; s < 8; s++) ISSUE(s);

    int area = 0, sumx = 0, sumy = 0;
    int minx = Ww, maxx = -1, miny = Hh, maxy = -1;

    for (int c = 0; c < 67; c++) {
      asm volatile("s_waitcnt vmcnt(7)" ::: "memory");   // chunk c landed
      __builtin_amdgcn_sched_barrier(0);
      STAT_BODY(c)
      __builtin_amdgcn_sched_barrier(0);                 // keep uses above
      ISSUE(c + 8);                                      // refill slot c&7
    }
    asm volatile("s_waitcnt vmcnt(0)" ::: "memory");     // drain tail
    __builtin_amdgcn_sched_barrier(0);
#pragma unroll
    for (int c = 67; c < 75; c++) STAT_BODY(c)
#undef ISSUE
#undef STAT_BODY

    for (int off = 32; off; off >>= 1) {
      area += __shfl_down(area, off);
      sumx += __shfl_down(sumx, off);
      sumy += __shfl_down(sumy, off);
      minx = min(minx, __shfl_down(minx, off));
      maxx = max(maxx, __shfl_down(maxx, off));
      miny = min(miny, __shfl_down(miny, off));
      maxy = max(maxy, __shfl_down(maxy, off));
    }
    if (lane == 0) {
      gstat[w * 7 + 0] = area; gstat[w * 7 + 1] = sumx; gstat[w * 7 + 2] = sumy;
      gstat[w * 7 + 3] = minx; gstat[w * 7 + 4] = maxx;
      gstat[w * 7 + 5] = miny; gstat[w * 7 + 6] = maxy;
    }
  } else {
    // ============ CONSUMER (4 waves): sample + pool + GEMV1 K<1024 =========
    const int cw   = w - 12;        // 0..3
    const int base = cw * 64 + lane;  // float4 col index owned by this lane

    // --- per-wave act list: 9 rounds of ballot compaction (no barrier) ---
    int mv[9];
#pragma unroll
    for (int r = 0; r < 9; r++) {
      int p = r * 64 + lane;        // p < 576 always
      int a = p / 24, c = p - a * 24;
      mv[r] = mbase[(a * 20) * Ww + c * 20];
    }
    int na = 0;
    int* actp = actw + cw * 576;
#pragma unroll
    for (int r = 0; r < 9; r++) {
      unsigned long long bal = __ballot(mv[r] > 0);
      int idx = __popcll(bal & ((1ull << lane) - 1));
      if (mv[r] > 0) actp[na + idx] = r * 64 + lane;
      na += __popcll(bal);
    }

    // --- pooling over own list (ascending row order, L2-served fm) ---
    const float4* fmp = (const float4*)fm + (size_t)b * Nn * (Dd / 4);
    float ax = 0.f, ay = 0.f, az = 0.f, aw = 0.f;
    int j = 0;
    for (; j + 4 <= na; j += 4) {
      int n0 = actp[j], n1 = actp[j + 1], n2 = actp[j + 2], n3 = actp[j + 3];
      float4 f0 = fmp[n0 * (Dd / 4) + base];
      float4 f1 = fmp[n1 * (Dd / 4) + base];
      float4 f2 = fmp[n2 * (Dd / 4) + base];
      float4 f3 = fmp[n3 * (Dd / 4) + base];
      ax += f0.x + f1.x + f2.x + f3.x;
      ay += f0.y + f1.y + f2.y + f3.y;
      az += f0.z + f1.z + f2.z + f3.z;
      aw += f0.w + f1.w + f2.w + f3.w;
    }
    for (; j < na; j++) {
      float4 f = fmp[actp[j] * (Dd / 4) + base];
      ax += f.x; ay += f.y; az += f.z; aw += f.w;
    }
    float inv = 1.0f / fmaxf((float)na, 1e-6f);
    float4 xp;
    xp.x = ax * inv; xp.y = ay * inv; xp.z = az * inv; xp.w = aw * inv;
    x4s[base] = xp;                 // same-wave LDS stage (no barrier needed)

    // --- GEMV1 over this wave's own K-slice [256cw, 256cw+256) ---
    float4 acc = {0.f, 0.f, 0.f, 0.f};
    const float* W1b = W1 + (size_t)(cw * 256) * OUTD + 4 * lane;
#pragma unroll 2
    for (int g = 0; g < 64; g++) {
      float4 xv = x4s[cw * 64 + g]; // wave-uniform LDS broadcast
      const float* xs = (const float*)&xv;
#pragma unroll
      for (int u = 0; u < 4; u++) {
        float4 w4 = *(const float4*)(W1b + (size_t)(4 * g + u) * OUTD);
        acc.x = fmaf(xs[u], w4.x, acc.x);
        acc.y = fmaf(xs[u], w4.y, acc.y);
        acc.z = fmaf(xs[u], w4.z, acc.z);
        acc.w = fmaf(xs[u], w4.w, acc.w);
      }
    }
    *(float4*)(partial + cw * 256 + 4 * lane) = acc;
  }
  __syncthreads();

  // ---------------- Epilogue ----------------
  if (t == 0) {
    int area = 0, sumx = 0, sumy = 0;
    int minx = Ww, maxx = -1, miny = Hh, maxy = -1;
#pragma unroll
    for (int i = 0; i < 12; i++) {
      area += gstat[i * 7 + 0]; sumx += gstat[i * 7 + 1]; sumy += gstat[i * 7 + 2];
      minx = min(minx, gstat[i * 7 + 3]); maxx = max(maxx, gstat[i * 7 + 4]);
      miny = min(miny, gstat[i * 7 + 5]); maxy = max(maxy, gstat[i * 7 + 6]);
    }
    float areaf = (float)area;
    float safe  = fmaxf(areaf, 1.0f);
    float cx = ((float)sumx / safe) * (1.0f / Ww);
    float cy = ((float)sumy / safe) * (1.0f / Hh);
    float an = areaf * (1.0f / (Hh * Ww));
    float bw = (float)(maxx - minx + 1) * (1.0f / Ww);
    float bh = (float)(maxy - miny + 1) * (1.0f / Hh);
    if (area < 1) { cx = 0.f; cy = 0.f; an = 0.f; bw = 0.f; bh = 0.f; }
    gmeta[0] = cx; gmeta[1] = cy; gmeta[2] = an; gmeta[3] = bw; gmeta[4] = bh;
  }
  __syncthreads();

  // combine + cls/geom GEMV1 tail + GeLU  (threads 0..255)
  float hv = 0.f;
  if (t < 256) {
    hv = b1[t] + partial[t] + partial[256 + t] + partial[512 + t] + partial[768 + t];
    const float* et = emb + (size_t)cids[bk] * CLSD;
#pragma unroll 8
    for (int i = 0; i < CLSD; i++)
      hv = fmaf(et[i], W1[(size_t)(Dd + i) * OUTD + t], hv);
#pragma unroll
    for (int jj = 0; jj < 5; jj++)
      hv = fmaf(gmeta[jj], W1[(size_t)(Dd + CLSD + jj) * OUTD + t], hv);
    hv = 0.5f * hv * (1.0f + erff(hv * 0.7071067811865475f));
  }
  {
    float s = hv, q = hv * hv;
    for (int off = 32; off; off >>= 1) {
      s += __shfl_down(s, off);
      q += __shfl_down(q, off);
    }
    if (lane == 0 && w < 4) { red_s[w] = s; red_q[w] = q; }
  }
  __syncthreads();
  if (t < 256) {
    float s = red_s[0] + red_s[1] + red_s[2] + red_s[3];
    float q = red_q[0] + red_q[1] + red_q[2] + red_q[3];
    float mu  = s * (1.0f / OUTD);
    float var = q * (1.0f / OUTD) - mu * mu;
    float ist = 1.0f / sqrtf(var + 1e-5f);
    hrow[t] = (hv - mu) * ist * lg[t] + lb[t];
  }
  __syncthreads();

  // GEMV2: 16-way wave K-split, float4 W2 loads
  {
    float4 acc = {0.f, 0.f, 0.f, 0.f};
#pragma unroll
    for (int i = 0; i < 4; i++) {
      float4 h4 = ((const float4*)hrow)[w * 4 + i];
      const float* hs = (const float*)&h4;
#pragma unroll
      for (int u = 0; u < 4; u++) {
        int kk = w * 16 + i * 4 + u;
        float4 w4 = *(const float4*)(W2 + (size_t)kk * OUTD + 4 * lane);
        acc.x = fmaf(hs[u], w4.x, acc.x);
        acc.y = fmaf(hs[u], w4.y, acc.y);
        acc.z = fmaf(hs[u], w4.z, acc.z);
        acc.w = fmaf(hs[u], w4.w, acc.w);
      }
    }
    *(float4*)(partial + w * 256 + 4 * lane) = acc;
  }
  __syncthreads();

  if (t < 256) {
    float c = b2[t];
#pragma unroll
    for (int ww = 0; ww < 16; ww++) c += partial[ww * 256 + t];
    __builtin_nontemporal_store(c, out + (size_t)bk * OUTD + t);
  }
}

extern "C" void kernel_launch(void* const* d_in, const int* in_sizes, int n_in,
                              void* d_out, int out_size, void* d_ws, size_t ws_size,
                              hipStream_t stream) {
  const float* fm    = (const float*)d_in[0];
  const int*   masks = (const int*)d_in[1];
  const int*   cids  = (const int*)d_in[2];
  const float* emb   = (const float*)d_in[3];
  const float* W1    = (const float*)d_in[4];
  const float* b1    = (const float*)d_in[5];
  const float* lg    = (const float*)d_in[6];
  const float* lb    = (const float*)d_in[7];
  const float* W2    = (const float*)d_in[8];
  const float* b2    = (const float*)d_in[9];
  float* out = (float*)d_out;

  hipLaunchKernelGGL(kF, dim3(BK), dim3(1024), SMEM_BYTES, stream, masks, fm,
                     cids, emb, W1, b1, lg, lb, W2, b2, out);
}

// Round 6
// 369.577 us; speedup vs baseline: 1.3769x; 1.0551x over previous
//
#include <hip/hip_runtime.h>
#include <math.h>

// Problem constants
#define Bb 8
#define Kk 32
#define Hh 480
#define Ww 480
#define Nn 576
#define Dd 1024
#define CLSD 64
#define OUTD 256
#define INDIM 1093
#define BK 256           // B*K

typedef int v4i __attribute__((ext_vector_type(4)));

// BEST-KNOWN KERNEL (R1 structure, 370.45 us): overlap-structured, one
// 1024-thread block per (b,k).
//   Waves 0-11 : full-res mask scan for geom stats (per-CU read-cap bound:
//                ~14 GB/s/CU; wave count / cache hints / DMA depth all
//                A/B'd null-or-worse in R2/R0/R5).
//   Waves 12-15: ballot-compacted act lists, pooling (L2-served fm),
//                GEMV1 over own 256-wide K-slice. No cross-wave deps.
//   Epilogue: geom finalize, cls-emb + geom GEMV1 tail, GeLU, LN, GEMV2.
// b = blockIdx%8: the 32 k-blocks of one b share an XCD L2 (fm slice 2.36MB).
__global__ __launch_bounds__(1024) void kF(const int* __restrict__ masks,
                                           const float* __restrict__ fm,
                                           const int* __restrict__ cids,
                                           const float* __restrict__ emb,
                                           const float* __restrict__ W1,
                                           const float* __restrict__ b1,
                                           const float* __restrict__ lg,
                                           const float* __restrict__ lb,
                                           const float* __restrict__ W2,
                                           const float* __restrict__ b2,
                                           float* __restrict__ out) {
  const int b    = blockIdx.x & 7;
  const int k    = blockIdx.x >> 3;
  const int bk   = b * Kk + k;
  const int t    = threadIdx.x;
  const int lane = t & 63;
  const int w    = t >> 6;          // wave id 0..15

  __shared__ int    actw[4][576];   // per-consumer-wave act lists (9.2 KB)
  __shared__ float4 x4s[256];       // per-consumer-wave x staging (4 KB)
  __shared__ float  partial[16 * 256]; // GEMV partials (16 KB)
  __shared__ float  hrow[256];
  __shared__ float  red_s[4], red_q[4];
  __shared__ float  gmeta[8];
  __shared__ int    gstat[12][7];   // per-scan-wave area,sumx,sumy,minx,maxx,miny,maxy

  const int* mbase = masks + (size_t)bk * (Hh * Ww);

  if (w < 12) {
    // ============ SCAN (768 threads, 75 clean iterations, nt loads) ========
    int area = 0, sumx = 0, sumy = 0;
    int minx = Ww, maxx = -1, miny = Hh, maxy = -1;
    const v4i* mp = (const v4i*)mbase;
#pragma unroll 5
    for (int i = 0; i < 75; i++) {
      int q = t + i * 768;
      v4i v = __builtin_nontemporal_load(mp + q);
      int h   = q / 120;            // 120 int4 per row (magic-mul)
      int rem = q - h * 120;
      int w0  = rem * 4;
      int m0 = v.x > 0, m1 = v.y > 0, m2 = v.z > 0, m3 = v.w > 0;
      int c = m0 + m1 + m2 + m3;
      area += c;
      sumy += h * c;
      sumx += w0 * c + m1 + 2 * m2 + 3 * m3;
      if (c) {
        miny = min(miny, h);
        maxy = max(maxy, h);
        int lo = m0 ? w0 : (m1 ? w0 + 1 : (m2 ? w0 + 2 : w0 + 3));
        int hi = m3 ? w0 + 3 : (m2 ? w0 + 2 : (m1 ? w0 + 1 : w0));
        minx = min(minx, lo);
        maxx = max(maxx, hi);
      }
    }
    for (int off = 32; off; off >>= 1) {
      area += __shfl_down(area, off);
      sumx += __shfl_down(sumx, off);
      sumy += __shfl_down(sumy, off);
      minx = min(minx, __shfl_down(minx, off));
      maxx = max(maxx, __shfl_down(maxx, off));
      miny = min(miny, __shfl_down(miny, off));
      maxy = max(maxy, __shfl_down(maxy, off));
    }
    if (lane == 0) {
      gstat[w][0] = area; gstat[w][1] = sumx; gstat[w][2] = sumy;
      gstat[w][3] = minx; gstat[w][4] = maxx;
      gstat[w][5] = miny; gstat[w][6] = maxy;
    }
  } else {
    // ============ CONSUMER (4 waves): sample + pool + GEMV1 K<1024 =========
    const int cw   = w - 12;        // 0..3
    const int base = cw * 64 + lane;  // float4 col index owned by this lane

    // --- per-wave act list: 9 rounds of ballot compaction (no barrier) ---
    int mv[9];
#pragma unroll
    for (int r = 0; r < 9; r++) {
      int p = r * 64 + lane;        // p < 576 always
      int a = p / 24, c = p - a * 24;
      mv[r] = mbase[(a * 20) * Ww + c * 20];
    }
    int na = 0;
    int* actp = actw[cw];
#pragma unroll
    for (int r = 0; r < 9; r++) {
      unsigned long long bal = __ballot(mv[r] > 0);
      int idx = __popcll(bal & ((1ull << lane) - 1));
      if (mv[r] > 0) actp[na + idx] = r * 64 + lane;
      na += __popcll(bal);
    }

    // --- pooling over own list (ascending row order, L2-served fm) ---
    const float4* fmp = (const float4*)fm + (size_t)b * Nn * (Dd / 4);
    float ax = 0.f, ay = 0.f, az = 0.f, aw = 0.f;
    int j = 0;
    for (; j + 4 <= na; j += 4) {
      int n0 = actp[j], n1 = actp[j + 1], n2 = actp[j + 2], n3 = actp[j + 3];
      float4 f0 = fmp[n0 * (Dd / 4) + base];
      float4 f1 = fmp[n1 * (Dd / 4) + base];
      float4 f2 = fmp[n2 * (Dd / 4) + base];
      float4 f3 = fmp[n3 * (Dd / 4) + base];
      ax += f0.x + f1.x + f2.x + f3.x;
      ay += f0.y + f1.y + f2.y + f3.y;
      az += f0.z + f1.z + f2.z + f3.z;
      aw += f0.w + f1.w + f2.w + f3.w;
    }
    for (; j < na; j++) {
      float4 f = fmp[actp[j] * (Dd / 4) + base];
      ax += f.x; ay += f.y; az += f.z; aw += f.w;
    }
    float inv = 1.0f / fmaxf((float)na, 1e-6f);
    float4 xp;
    xp.x = ax * inv; xp.y = ay * inv; xp.z = az * inv; xp.w = aw * inv;
    x4s[base] = xp;                 // same-wave LDS stage (no barrier needed)

    // --- GEMV1 over this wave's own K-slice [256cw, 256cw+256) ---
    float4 acc = {0.f, 0.f, 0.f, 0.f};
    const float* W1b = W1 + (size_t)(cw * 256) * OUTD + 4 * lane;
#pragma unroll 2
    for (int g = 0; g < 64; g++) {
      float4 xv = x4s[cw * 64 + g]; // wave-uniform LDS broadcast
      const float* xs = (const float*)&xv;
#pragma unroll
      for (int u = 0; u < 4; u++) {
        float4 w4 = *(const float4*)(W1b + (size_t)(4 * g + u) * OUTD);
        acc.x = fmaf(xs[u], w4.x, acc.x);
        acc.y = fmaf(xs[u], w4.y, acc.y);
        acc.z = fmaf(xs[u], w4.z, acc.z);
        acc.w = fmaf(xs[u], w4.w, acc.w);
      }
    }
    *(float4*)(partial + cw * 256 + 4 * lane) = acc;
  }
  __syncthreads();

  // ---------------- Epilogue ----------------
  if (t == 0) {
    int area = 0, sumx = 0, sumy = 0;
    int minx = Ww, maxx = -1, miny = Hh, maxy = -1;
#pragma unroll
    for (int i = 0; i < 12; i++) {
      area += gstat[i][0]; sumx += gstat[i][1]; sumy += gstat[i][2];
      minx = min(minx, gstat[i][3]); maxx = max(maxx, gstat[i][4]);
      miny = min(miny, gstat[i][5]); maxy = max(maxy, gstat[i][6]);
    }
    float areaf = (float)area;
    float safe  = fmaxf(areaf, 1.0f);
    float cx = ((float)sumx / safe) * (1.0f / Ww);
    float cy = ((float)sumy / safe) * (1.0f / Hh);
    float an = areaf * (1.0f / (Hh * Ww));
    float bw = (float)(maxx - minx + 1) * (1.0f / Ww);
    float bh = (float)(maxy - miny + 1) * (1.0f / Hh);
    if (area < 1) { cx = 0.f; cy = 0.f; an = 0.f; bw = 0.f; bh = 0.f; }
    gmeta[0] = cx; gmeta[1] = cy; gmeta[2] = an; gmeta[3] = bw; gmeta[4] = bh;
  }
  __syncthreads();

  // combine + cls/geom GEMV1 tail + GeLU  (threads 0..255)
  float hv = 0.f;
  if (t < 256) {
    hv = b1[t] + partial[t] + partial[256 + t] + partial[512 + t] + partial[768 + t];
    const float* et = emb + (size_t)cids[bk] * CLSD;
#pragma unroll 8
    for (int i = 0; i < CLSD; i++)
      hv = fmaf(et[i], W1[(size_t)(Dd + i) * OUTD + t], hv);
#pragma unroll
    for (int jj = 0; jj < 5; jj++)
      hv = fmaf(gmeta[jj], W1[(size_t)(Dd + CLSD + jj) * OUTD + t], hv);
    hv = 0.5f * hv * (1.0f + erff(hv * 0.7071067811865475f));
  }
  {
    float s = hv, q = hv * hv;
    for (int off = 32; off; off >>= 1) {
      s += __shfl_down(s, off);
      q += __shfl_down(q, off);
    }
    if (lane == 0 && w < 4) { red_s[w] = s; red_q[w] = q; }
  }
  __syncthreads();
  if (t < 256) {
    float s = red_s[0] + red_s[1] + red_s[2] + red_s[3];
    float q = red_q[0] + red_q[1] + red_q[2] + red_q[3];
    float mu  = s * (1.0f / OUTD);
    float var = q * (1.0f / OUTD) - mu * mu;
    float ist = 1.0f / sqrtf(var + 1e-5f);
    hrow[t] = (hv - mu) * ist * lg[t] + lb[t];
  }
  __syncthreads();

  // GEMV2: 16-way wave K-split, float4 W2 loads
  {
    float4 acc = {0.f, 0.f, 0.f, 0.f};
#pragma unroll
    for (int i = 0; i < 4; i++) {
      float4 h4 = ((const float4*)hrow)[w * 4 + i];
      const float* hs = (const float*)&h4;
#pragma unroll
      for (int u = 0; u < 4; u++) {
        int kk = w * 16 + i * 4 + u;
        float4 w4 = *(const float4*)(W2 + (size_t)kk * OUTD + 4 * lane);
        acc.x = fmaf(hs[u], w4.x, acc.x);
        acc.y = fmaf(hs[u], w4.y, acc.y);
        acc.z = fmaf(hs[u], w4.z, acc.z);
        acc.w = fmaf(hs[u], w4.w, acc.w);
      }
    }
    *(float4*)(partial + w * 256 + 4 * lane) = acc;
  }
  __syncthreads();

  if (t < 256) {
    float c = b2[t];
#pragma unroll
    for (int ww = 0; ww < 16; ww++) c += partial[ww * 256 + t];
    __builtin_nontemporal_store(c, out + (size_t)bk * OUTD + t);
  }
}

extern "C" void kernel_launch(void* const* d_in, const int* in_sizes, int n_in,
                              void* d_out, int out_size, void* d_ws, size_t ws_size,
                              hipStream_t stream) {
  const float* fm    = (const float*)d_in[0];
  const int*   masks = (const int*)d_in[1];
  const int*   cids  = (const int*)d_in[2];
  const float* emb   = (const float*)d_in[3];
  const float* W1    = (const float*)d_in[4];
  const float* b1    = (const float*)d_in[5];
  const float* lg    = (const float*)d_in[6];
  const float* lb    = (const float*)d_in[7];
  const float* W2    = (const float*)d_in[8];
  const float* b2    = (const float*)d_in[9];
  float* out = (float*)d_out;

  hipLaunchKernelGGL(kF, dim3(BK), dim3(1024), 0, stream, masks, fm, cids, emb,
                     W1, b1, lg, lb, W2, b2, out);
}